// Round 5
// baseline (458.965 us; speedup 1.0000x reference)
//
#include <hip/hip_runtime.h>
#include <hip/hip_fp16.h>

#define N_ 32
#define C_ 512
#define P_ 1024
#define S_ 2048
#define NR_ (N_ * P_)   // 32768 rows
#define GUARD 6e-3f     // ~30 sigma of bf16-score diff noise; np-rescore set radius
#define TSIG 2.3f       // candidate threshold in row-sigma units

typedef __attribute__((ext_vector_type(8))) short sh8;
typedef __attribute__((ext_vector_type(4))) float fx4;

// ---- ws layout (bytes) ----
#define WS_XT       0ull            // ushort bf16 [32768][512] = 33554432
#define WS_XTF      33554432ull     // float [32768][512]       = 67108864
#define WS_CBT      100663296ull    // ushort bf16 [2048][512]  = 2097152
#define WS_C2F      102760448ull    // float [2048]             = 8192
#define WS_X2       102768640ull    // float [32768]            = 131072
#define WS_CNT      102899712ull    // int [32768]              = 131072
#define WS_CANDV    103030784ull    // float [32768][64]        = 8388608
#define WS_CANDS    111419392ull    // int [32768][64]          = 8388608
#define WS_ROWPART  119808000ull    // double [32768]           = 262144
#define WS_COMMIT   120070144ull    // double [16384]           = 131072
#define WS_TOTAL    120201216ull

#define TBLK 1024       // transpose blocks in k_prep (32 rows each)
#define CVTBLK 512      // cvt blocks in k_prep (4 cb rows each)

__device__ __forceinline__ unsigned short f2bf(float f) {
  union { float f; unsigned u; } x; x.f = f;
  unsigned r = x.u + 0x7fffu + ((x.u >> 16) & 1u);
  return (unsigned short)(r >> 16);
}

template <typename T>
__device__ __forceinline__ void load16_lds(const T* g, T* l) {
  __builtin_amdgcn_global_load_lds((const __attribute__((address_space(1))) void*)g,
                                   (__attribute__((address_space(3))) void*)l, 16, 0, 0);
}

// ---------------- k_prep: fused {transpose+cvt x, np x2 chain, cnt=0} + {cvt cb, c2} --
// 32-p blocks, two 256-c passes: every x-read is a 128-B contiguous segment
// (8 lanes x float4 per c-row) -> full cache-line utilization.
__global__ __launch_bounds__(256) void k_prep(const float* __restrict__ x,
                                              const float* __restrict__ cb,
                                              unsigned short* __restrict__ xT,
                                              float* __restrict__ xTf,
                                              unsigned short* __restrict__ cbT,
                                              float* __restrict__ c2f,
                                              float* __restrict__ x2ws,
                                              int* __restrict__ cnt) {
  __shared__ float tile[32][260];   // 33 KB; stride 260 floats = 1040 B (16B-aligned)
  const int tid = threadIdx.x;
  const int bx = blockIdx.x;

  if (bx < TBLK) {
    const int n = bx >> 5;
    const int p0 = (bx & 31) << 5;           // 32 p's per block
    const float* xb = x + (size_t)n * (C_ * P_) + p0;
    const int p4 = (tid & 7) << 2;           // 8 lanes x float4 = 32 p's
    const int ch = tid >> 3;                 // 32 c-rows per iteration

    float acc = 0.f;                         // np-exact x2 chain, ascending c
#pragma unroll
    for (int pass = 0; pass < 2; ++pass) {
      if (pass) __syncthreads();             // tile reuse
      // ---- load 32 p x 256 c (128-B contiguous per c-row) ----
#pragma unroll
      for (int it = 0; it < 8; ++it) {
        int cl = (it << 5) + ch;
        float4 v = *(const float4*)(xb + (size_t)(pass * 256 + cl) * P_ + p4);
        tile[p4 + 0][cl] = v.x;
        tile[p4 + 1][cl] = v.y;
        tile[p4 + 2][cl] = v.z;
        tile[p4 + 3][cl] = v.w;
      }
      __syncthreads();

      // xTf (fp32 rows) + xT (bf16 rows), contiguous writes: 32 rows x 256 c
#pragma unroll
      for (int it = 0; it < 8; ++it) {
        int idx = tid + 256 * it;            // 0..2047 float4s
        int row = idx >> 6, c4 = (idx & 63) << 2;
        float4 f = *(const float4*)&tile[row][c4];
        size_t R = (size_t)((n << 10) + p0 + row);
        size_t cg = (size_t)pass * 256 + c4;
        *(float4*)(xTf + R * C_ + cg) = f;
        ushort4 o;
        o.x = f2bf(f.x); o.y = f2bf(f.y); o.z = f2bf(f.z); o.w = f2bf(f.w);
        *(ushort4*)(xT + R * C_ + cg) = o;
      }

      // np-exact x2: strict sequential fp32 chain over c (ascending), no FMA
      if (tid < 32) {
        for (int c = 0; c < 256; ++c) {
          float t = tile[tid][c];
          acc = __fadd_rn(acc, __fmul_rn(t, t));
        }
      }
    }
    if (tid < 32) {
      int R = (n << 10) + p0 + tid;
      x2ws[R] = acc;
      cnt[R] = 0;
    }
  } else {
    // ---- cvt codebook rows to bf16 + c2 (fp64 sum of fp32 squares -> fp32) ----
    const int s = (bx - TBLK) * 4 + (tid >> 6);
    const int l = tid & 63;
    const float* row = cb + (size_t)s * C_;
    double c2d = 0.0;
#pragma unroll
    for (int h = 0; h < 2; ++h) {
      int c = h * 256 + l * 4;
      float4 v = *(const float4*)(row + c);
      ushort4 o;
      o.x = f2bf(v.x); o.y = f2bf(v.y); o.z = f2bf(v.z); o.w = f2bf(v.w);
      *(ushort4*)(cbT + (size_t)s * C_ + c) = o;
      c2d += (double)__fmul_rn(v.x, v.x) + (double)__fmul_rn(v.y, v.y) +
             (double)__fmul_rn(v.z, v.z) + (double)__fmul_rn(v.w, v.w);
    }
#pragma unroll
    for (int off = 32; off > 0; off >>= 1) c2d += __shfl_down(c2d, off);
    if (l == 0) c2f[s] = (float)c2d;
  }
}

// ---------------- MFMA GEMM + threshold epilogue -> per-row candidate lists -------
// 128x128 tile, BK=64, 4 waves, 4 blocks/CU (round-0 K-loop, measured 130 us).
// Epilogue v2: TWO-PASS, atomic-pipelined. Pass 1 issues all 16 atomicAdds
// back-to-back (16 in flight -> one ~600cy latency instead of 16 serialized);
// pass 2 recomputes masks and does the appends. Appends per row are an
// unordered set (phase2 ranks by value), so reordering preserves semantics.
__global__ __launch_bounds__(256, 4) void k_gemm(const unsigned short* __restrict__ xT,
                                                 const unsigned short* __restrict__ cbT,
                                                 const float* __restrict__ x2ws,
                                                 float* __restrict__ candv,
                                                 int* __restrict__ cands,
                                                 int* __restrict__ cnt) {
  __shared__ unsigned short As[128 * 64];  // 16 KB, chunk (m*8 + (k8 ^ (m&7)))
  __shared__ unsigned short Bs[128 * 64];
  __shared__ float t_lds[128];
  const int tid = threadIdx.x;
  const int w = tid >> 6, l = tid & 63;
  const int bx = blockIdx.x;
  // XCD-aware swizzle: xcd = bx&7 fixed per m-tile, s-tile = (bx>>3)&15
  const int m_tile = ((bx >> 7) << 3) + (bx & 7);
  const int s_tile = (bx >> 3) & 15;
  const int m0 = m_tile << 7, s0 = s_tile << 7;
  const int wm = (w & 1) << 6, wsf = (w >> 1) << 6;
  const int quad = l >> 4, lane15 = l & 15;

  if (tid < 128) t_lds[tid] = TSIG * __fsqrt_rn(x2ws[m0 + tid]) * (1.0f / 512.0f);

  size_t gA[4], gB[4];
  unsigned short *lA[4], *lB[4];
#pragma unroll
  for (int q = 0; q < 4; ++q) {
    int chunk = (q * 4 + w) * 64 + l;
    int m = chunk >> 3, k8s = chunk & 7;
    int k8 = k8s ^ (m & 7);
    gA[q] = (size_t)(m0 + m) * (C_ * 2) + (size_t)k8 * 16;
    gB[q] = (size_t)(s0 + m) * (C_ * 2) + (size_t)k8 * 16;
    lA[q] = As + (q * 4 + w) * 512;
    lB[q] = Bs + (q * 4 + w) * 512;
  }
  const char* xb = (const char*)xT;
  const char* cbb = (const char*)cbT;

  fx4 acc[4][4];
#pragma unroll
  for (int i = 0; i < 4; ++i)
#pragma unroll
    for (int j = 0; j < 4; ++j) acc[i][j] = (fx4){0.f, 0.f, 0.f, 0.f};

  for (int kk = 0; kk < 8; ++kk) {
#pragma unroll
    for (int q = 0; q < 4; ++q) {
      load16_lds((const unsigned short*)(xb + gA[q] + (size_t)kk * 128), lA[q]);
      load16_lds((const unsigned short*)(cbb + gB[q] + (size_t)kk * 128), lB[q]);
    }
    __syncthreads();
#pragma unroll
    for (int ks = 0; ks < 2; ++ks) {
      const int k8g = ks * 4 + quad;
      sh8 af[4], bf[4];
#pragma unroll
      for (int mi = 0; mi < 4; ++mi) {
        int m = wm + mi * 16 + lane15;
        af[mi] = *(const sh8*)(As + m * 64 + (k8g ^ (m & 7)) * 8);
      }
#pragma unroll
      for (int si = 0; si < 4; ++si) {
        int s = wsf + si * 16 + lane15;
        bf[si] = *(const sh8*)(Bs + s * 64 + (k8g ^ (s & 7)) * 8);
      }
#pragma unroll
      for (int mi = 0; mi < 4; ++mi)
#pragma unroll
        for (int si = 0; si < 4; ++si)
          acc[mi][si] = __builtin_amdgcn_mfma_f32_16x16x32_bf16(af[mi], bf[si], acc[mi][si], 0, 0, 0);
    }
    __syncthreads();
  }

  // ---- Epilogue pass 1: totals + issue ALL atomics (pipelined in flight) ----
  // C/D layout: row = wm+mi*16+quad*4+r, col = s0+wsf+si*16+lane15.
  int baseReg[16];
#pragma unroll
  for (int mi = 0; mi < 4; ++mi) {
#pragma unroll
    for (int r = 0; r < 4; ++r) {
      const int it = mi * 4 + r;
      const int rowl = wm + mi * 16 + quad * 4 + r;
      const int rowg = m0 + rowl;
      const float t = t_lds[rowl];
      int total = 0;
#pragma unroll
      for (int si = 0; si < 4; ++si) {
        unsigned long long b = __ballot(acc[mi][si][r] >= t);
        total += __popc((unsigned)((b >> (quad * 16)) & 0xFFFFull));
      }
      baseReg[it] = 0;
      if (lane15 == 0) baseReg[it] = atomicAdd(&cnt[rowg], total > 0 ? total : 1);
    }
  }

  // ---- Epilogue pass 2: recompute masks, retire atomics one-by-one, append ----
  const unsigned below = (1u << lane15) - 1u;
#pragma unroll
  for (int mi = 0; mi < 4; ++mi) {
#pragma unroll
    for (int r = 0; r < 4; ++r) {
      const int it = mi * 4 + r;
      const int rowl = wm + mi * 16 + quad * 4 + r;
      const int rowg = m0 + rowl;
      const float t = t_lds[rowl];
      float v[4]; int scol[4]; bool hit[4];
      float vmax = -1e30f; int smax = 0;
#pragma unroll
      for (int si = 0; si < 4; ++si) {
        v[si] = acc[mi][si][r];
        scol[si] = s0 + wsf + si * 16 + lane15;
        hit[si] = v[si] >= t;
        if (v[si] > vmax) { vmax = v[si]; smax = scol[si]; }
      }
      int total = 0, myslot[4];
#pragma unroll
      for (int si = 0; si < 4; ++si) {
        unsigned long long b = __ballot(hit[si]);
        unsigned seg = (unsigned)((b >> (quad * 16)) & 0xFFFFull);
        myslot[si] = total + __popc(seg & below);
        total += __popc(seg);
      }
      // 16-lane segment max reduce (offsets < 16 stay in segment)
#pragma unroll
      for (int off = 1; off < 16; off <<= 1) {
        float ov = __shfl_xor(vmax, off);
        int os = __shfl_xor(smax, off);
        if (ov > vmax) { vmax = ov; smax = os; }
      }
      int base = __shfl(baseReg[it], quad * 16);
      if (total > 0) {
#pragma unroll
        for (int si = 0; si < 4; ++si) {
          if (hit[si]) {
            int slot = base + myslot[si];
            if (slot < 64) {
              candv[(size_t)rowg * 64 + slot] = v[si];
              cands[(size_t)rowg * 64 + slot] = scol[si];
            }
          }
        }
      } else if (lane15 == 0 && base < 64) {
        candv[(size_t)rowg * 64 + base] = vmax;
        cands[(size_t)rowg * 64 + base] = smax;
      }
    }
  }
}

// ---------------- phase 2: ranks/loss from d~, lazy np-fp32 rescore for argmin ----
// Rank loop via LDS broadcast float4/int4 reads (32 DS-ops) instead of 64x2
// serial shuffles (128 DS-ops). Same comparisons, same order, identical rank.
__global__ __launch_bounds__(256, 4) void k_phase2(
    const float* __restrict__ cb, const float* __restrict__ xTf,
    const float* __restrict__ candvG, const int* __restrict__ candsG,
    const int* __restrict__ cntG, const float* __restrict__ c2f,
    const float* __restrict__ x2ws, float* __restrict__ out,
    double* __restrict__ rowpart) {
  __shared__ float xrow[4][C_];
  __shared__ float dt_l[4][64];
  __shared__ int s_l[4][64];
  const int tid = threadIdx.x;
  const int w = tid >> 6, l = tid & 63;
  const int R = blockIdx.x * 4 + w;

  const int cnt = min(cntG[R], 64);
  const float x2f = x2ws[R];
  const bool act = l < cnt;
  float v = candvG[(size_t)R * 64 + l];
  int s = candsG[(size_t)R * 64 + l];
  v = act ? v : -1e30f;
  s = act ? s : 0x7fffffff;
  const int sIdx = act ? s : 0;
  const float dt = act
      ? __fsub_rn(__fadd_rn(x2f, c2f[sIdx]), __fmul_rn(2.f, v))
      : 1e30f;

  float M = v;
#pragma unroll
  for (int off = 1; off < 64; off <<= 1) M = fmaxf(M, __shfl_xor(M, off));

  dt_l[w][l] = dt;
  s_l[w][l] = s;
  asm volatile("s_waitcnt lgkmcnt(0)" ::: "memory");  // same-wave LDS RAW

  int rank = 0;
#pragma unroll
  for (int k4 = 0; k4 < 16; ++k4) {
    float4 dk = *(const float4*)&dt_l[w][k4 * 4];
    int4 sk = *(const int4*)&s_l[w][k4 * 4];
    rank += (dk.x < dt || (dk.x == dt && sk.x < s)) ? 1 : 0;
    rank += (dk.y < dt || (dk.y == dt && sk.y < s)) ? 1 : 0;
    rank += (dk.z < dt || (dk.z == dt && sk.z < s)) ? 1 : 0;
    rank += (dk.w < dt || (dk.w == dt && sk.w < s)) ? 1 : 0;
  }

  double contrib = act ? (double)__expf(-(float)rank) * (double)dt : 0.0;
#pragma unroll
  for (int off = 32; off > 0; off >>= 1) contrib += __shfl_down(contrib, off);
  if (l == 0) rowpart[R] = contrib;

  const bool near = act && (v >= M - GUARD);
  const unsigned long long bal = __ballot(near);
  const int nres = __popcll(bal);
  if (nres == 1) {
    int src = __ffsll(bal) - 1;
    int wins = __shfl(s, src);
    if (l == 0) out[2 + R] = (float)wins;
  } else {
#pragma unroll
    for (int k = 0; k < 2; ++k)
      *(float4*)&xrow[w][l * 8 + k * 4] = *(const float4*)(xTf + (size_t)R * C_ + l * 8 + k * 4);
    float d32 = 1e30f;
    if (near) {
      const float4* crow = (const float4*)(cb + (size_t)s * C_);
      float acc = 0.f;
#pragma unroll 8
      for (int i = 0; i < C_ / 4; ++i) {
        float4 cv = crow[i];
        float4 xv = *(const float4*)&xrow[w][i * 4];
        acc = __fadd_rn(acc, __fmul_rn(xv.x, cv.x));
        acc = __fadd_rn(acc, __fmul_rn(xv.y, cv.y));
        acc = __fadd_rn(acc, __fmul_rn(xv.z, cv.z));
        acc = __fadd_rn(acc, __fmul_rn(xv.w, cv.w));
      }
      d32 = __fsub_rn(__fadd_rn(x2f, c2f[s]), __fmul_rn(2.f, acc));
    }
    float bd = d32;
    int bs2 = near ? s : 0x7fffffff;
#pragma unroll
    for (int off = 1; off < 64; off <<= 1) {
      float ov = __shfl_xor(bd, off);
      int os = __shfl_xor(bs2, off);
      if (ov < bd || (ov == bd && os < bs2)) { bd = ov; bs2 = os; }
    }
    if (l == 0) out[2 + R] = (float)bs2;
  }
}

// ---------------- K2: straight-through output + commitment loss ----------------
// p-tile-major: block = (n, 16 consecutive p's). Winner codebook rows staged
// CONTIGUOUSLY into LDS (16 x 2KB reads), eliminating the per-element random
// 4B-from-64B-line gather. Commitment partials keep the (c, aligned-4-p)
// grouping and accumulation order; only the double tree reassociates.
__global__ __launch_bounds__(256) void k2_output(
    const float* __restrict__ x, const float* __restrict__ cb,
    float* __restrict__ out, double* __restrict__ commit_partial) {
  __shared__ float qt[16][516];   // 33 KB; pad 4 -> 16B-aligned rows, <=2-way banks
  __shared__ int s_lds[16];
  __shared__ double r2[4];
  const int tid = threadIdx.x;
  const int bx = blockIdx.x;
  const int n = bx >> 6;
  const int p0 = (bx & 63) << 4;   // 16 p's per block

  if (tid < 16) s_lds[tid] = (int)out[2 + n * P_ + p0 + tid];
  __syncthreads();
  {
    const int p = tid >> 4, c0 = (tid & 15) << 2;
    const float* row = cb + (size_t)s_lds[p] * C_;
#pragma unroll
    for (int it = 0; it < 8; ++it) {
      int c = c0 + (it << 6);
      *(float4*)&qt[p][c] = *(const float4*)(row + c);
    }
  }
  __syncthreads();

  const int cl = tid >> 2, pq = (tid & 3) << 2;   // 64 c's/chunk x 4 p's/thread
  double dacc = 0.0;
#pragma unroll
  for (int chunk = 0; chunk < 8; ++chunk) {
    int c = (chunk << 6) + cl;
    const float* xr = x + ((size_t)n * C_ + c) * P_ + p0 + pq;
    float4 xv = *(const float4*)xr;
    float xs[4] = {xv.x, xv.y, xv.z, xv.w};
    float o[4];
    float acc = 0.f;
#pragma unroll
    for (int k = 0; k < 4; ++k) {
      float q = qt[pq + k][c];
      float t = __fsub_rn(q, xs[k]);
      o[k] = __fadd_rn(xs[k], t);
      float dd = __fsub_rn(xs[k], q);
      acc += dd * dd;
    }
    float* orow = out + 2 + N_ * P_ + ((size_t)n * C_ + c) * P_ + p0 + pq;
    *(float4*)orow = make_float4(o[0], o[1], o[2], o[3]);
    dacc += (double)acc;
  }

#pragma unroll
  for (int off = 32; off > 0; off >>= 1) dacc += __shfl_down(dacc, off);
  if ((tid & 63) == 0) r2[tid >> 6] = dacc;
  __syncthreads();
  if (tid == 0) commit_partial[bx] = r2[0] + r2[1] + r2[2] + r2[3];
}

// ---------------- K3: finalize scalars ----------------
__global__ __launch_bounds__(256) void k3_finalize(
    const double* __restrict__ pa, int na, const double* __restrict__ pb, int nb,
    float* __restrict__ out) {
  __shared__ double red[8];
  const int tid = threadIdx.x;
  double a = 0.0, b = 0.0;
  for (int i = tid; i < na; i += 256) a += pa[i];
  for (int i = tid; i < nb; i += 256) b += pb[i];
#pragma unroll
  for (int off = 32; off > 0; off >>= 1) {
    a += __shfl_down(a, off);
    b += __shfl_down(b, off);
  }
  if ((tid & 63) == 0) {
    red[(tid >> 6) * 2 + 0] = a;
    red[(tid >> 6) * 2 + 1] = b;
  }
  __syncthreads();
  if (tid == 0) {
    double A = red[0] + red[2] + red[4] + red[6];
    double B = red[1] + red[3] + red[5] + red[7];
    out[0] = (float)(A / ((double)N_ * (double)S_ * (double)P_));
    out[1] = (float)(B / ((double)N_ * (double)C_ * (double)P_));
  }
}

// ======================= round-2 fallback (small-ws path) =======================
#define TPW 8
#define KC 32
#define SC 64
#define KCF 48
__global__ __launch_bounds__(256) void k1_fallback(
    const float* __restrict__ x, const float* __restrict__ cb,
    float* __restrict__ out, double* __restrict__ cb_partial) {
  __shared__ float dval[TPW][KCF];
  __shared__ float x2f[TPW];
  __shared__ double redd[4];
  __shared__ float x_t[TPW][C_ + 4];
  __shared__ float cb_t[SC][KC + 4];
  __shared__ int cand_s[TPW][KCF];
  __shared__ _Float16 sc[S_][TPW];

  const int tid = threadIdx.x;
  const int bx = blockIdx.x;
  const int n = bx >> 7;
  const int p0 = (bx & 127) * TPW;

  const float* xn = x + (size_t)n * C_ * P_ + p0;
#pragma unroll
  for (int q = 0; q < 16; ++q) {
    int e = tid + 256 * q;
    int c = e >> 3, j = e & 7;
    x_t[j][c] = xn[(size_t)c * P_ + j];
  }
  __syncthreads();
  if (tid < TPW) {
    float acc = 0.f;
    for (int c = 0; c < C_; ++c)
      acc = __fadd_rn(acc, __fmul_rn(x_t[tid][c], x_t[tid][c]));
    x2f[tid] = acc;
  }
  const int j = tid & 7;
  const int sg = tid >> 3;
  for (int s0 = 0; s0 < S_; s0 += SC) {
    float acc0 = 0.f, acc1 = 0.f;
    for (int k0 = 0; k0 < C_; k0 += KC) {
      __syncthreads();
#pragma unroll
      for (int q = 0; q < 8; ++q) {
        int e = tid + 256 * q;
        int i = e >> 5, cc = e & 31;
        cb_t[i][cc] = cb[(size_t)(s0 + i) * C_ + k0 + cc];
      }
      __syncthreads();
      const float* xr = &x_t[j][k0];
#pragma unroll
      for (int cs = 0; cs < KC; cs += 4) {
        float4 xv = *(const float4*)(xr + cs);
        float4 a4 = *(const float4*)(&cb_t[sg][cs]);
        float4 b4 = *(const float4*)(&cb_t[sg + 32][cs]);
        acc0 += xv.x * a4.x + xv.y * a4.y + xv.z * a4.z + xv.w * a4.w;
        acc1 += xv.x * b4.x + xv.y * b4.y + xv.z * b4.z + xv.w * b4.w;
      }
    }
    sc[s0 + sg][j] = (_Float16)acc0;
    sc[s0 + sg + 32][j] = (_Float16)acc1;
  }
  __syncthreads();
  {
    const int g = tid >> 5, t = tid & 31;
    for (int pass = 0; pass < KCF; ++pass) {
      float bv = -1e30f;
      int bs = 0;
      for (int k = 0; k < 64; ++k) {
        int s = t + 32 * k;
        float vv = (float)sc[s][g];
        if (vv > bv) { bv = vv; bs = s; }
      }
#pragma unroll
      for (int off = 1; off < 32; off <<= 1) {
        float ov = __shfl_xor(bv, off);
        int os = __shfl_xor(bs, off);
        if (ov > bv || (ov == bv && os < bs)) { bv = ov; bs = os; }
      }
      if (t == 0) {
        cand_s[g][pass] = bs;
        sc[bs][g] = (_Float16)(-65504.f);
      }
      __syncthreads();
    }
  }
  for (int task = tid; task < TPW * KCF; task += 256) {
    int jj = task / KCF, r = task % KCF;
    int s = cand_s[jj][r];
    const float* row = cb + (size_t)s * C_;
    const float* xrw = &x_t[jj][0];
    float acc = 0.f;
    double c2d = 0.0;
    for (int c = 0; c < C_; c += 4) {
      float4 cv = *(const float4*)(row + c);
      acc = __fadd_rn(acc, __fmul_rn(xrw[c + 0], cv.x));
      acc = __fadd_rn(acc, __fmul_rn(xrw[c + 1], cv.y));
      acc = __fadd_rn(acc, __fmul_rn(xrw[c + 2], cv.z));
      acc = __fadd_rn(acc, __fmul_rn(xrw[c + 3], cv.w));
      c2d += (double)__fmul_rn(cv.x, cv.x);
      c2d += (double)__fmul_rn(cv.y, cv.y);
      c2d += (double)__fmul_rn(cv.z, cv.z);
      c2d += (double)__fmul_rn(cv.w, cv.w);
    }
    float c2s = (float)c2d;
    dval[jj][r] = __fsub_rn(__fadd_rn(x2f[jj], c2s), __fmul_rn(2.f, acc));
  }
  __syncthreads();
  double contrib = 0.0;
  for (int task = tid; task < TPW * KCF; task += 256) {
    int jj = task / KCF, r = task % KCF;
    float e = dval[jj][r];
    int s = cand_s[jj][r];
    int rank = 0;
    for (int r2 = 0; r2 < KCF; ++r2) {
      float e2 = dval[jj][r2];
      int s2 = cand_s[jj][r2];
      rank += (e2 < e || (e2 == e && s2 < s)) ? 1 : 0;
    }
    contrib += exp((double)(-rank)) * (double)e;
    if (rank == 0) out[2 + n * P_ + p0 + jj] = (float)s;
  }
  __syncthreads();
#pragma unroll
  for (int off = 32; off > 0; off >>= 1) contrib += __shfl_down(contrib, off);
  if ((tid & 63) == 0) redd[tid >> 6] = contrib;
  __syncthreads();
  if (tid == 0) cb_partial[bx] = redd[0] + redd[1] + redd[2] + redd[3];
}

extern "C" void kernel_launch(void* const* d_in, const int* in_sizes, int n_in,
                              void* d_out, int out_size, void* d_ws, size_t ws_size,
                              hipStream_t stream) {
  const float* x = (const float*)d_in[0];
  const float* cb = (const float*)d_in[1];
  float* out = (float*)d_out;
  char* ws = (char*)d_ws;

  if (ws_size >= WS_TOTAL) {
    unsigned short* xT = (unsigned short*)(ws + WS_XT);
    float* xTf = (float*)(ws + WS_XTF);
    unsigned short* cbT = (unsigned short*)(ws + WS_CBT);
    float* c2f = (float*)(ws + WS_C2F);
    float* x2ws = (float*)(ws + WS_X2);
    int* cnt = (int*)(ws + WS_CNT);
    float* candv = (float*)(ws + WS_CANDV);
    int* cands = (int*)(ws + WS_CANDS);
    double* rowpart = (double*)(ws + WS_ROWPART);
    double* commitp = (double*)(ws + WS_COMMIT);

    hipLaunchKernelGGL(k_prep, dim3(TBLK + CVTBLK), dim3(256), 0, stream,
                       x, cb, xT, xTf, cbT, c2f, x2ws, cnt);
    hipLaunchKernelGGL(k_gemm, dim3(4096), dim3(256), 0, stream,
                       xT, cbT, x2ws, candv, cands, cnt);
    hipLaunchKernelGGL(k_phase2, dim3(NR_ / 4), dim3(256), 0, stream,
                       cb, xTf, candv, cands, cnt, c2f, x2ws, out, rowpart);
    hipLaunchKernelGGL(k2_output, dim3(2048), dim3(256), 0, stream, x, cb, out, commitp);
    hipLaunchKernelGGL(k3_finalize, dim3(1), dim3(256), 0, stream,
                       rowpart, NR_, commitp, 2048, out);
  } else {
    double* cb_partial = (double*)d_ws;
    double* commitp = cb_partial + 4096;
    hipLaunchKernelGGL(k1_fallback, dim3(4096), dim3(256), 0, stream, x, cb, out, cb_partial);
    hipLaunchKernelGGL(k2_output, dim3(2048), dim3(256), 0, stream, x, cb, out, commitp);
    hipLaunchKernelGGL(k3_finalize, dim3(1), dim3(256), 0, stream,
                       cb_partial, 4096, commitp, 2048, out);
  }
}

// Round 6
// 446.436 us; speedup vs baseline: 1.0281x; 1.0281x over previous
//
#include <hip/hip_runtime.h>
#include <hip/hip_fp16.h>

#define N_ 32
#define C_ 512
#define P_ 1024
#define S_ 2048
#define NR_ (N_ * P_)   // 32768 rows
#define GUARD 6e-3f     // ~30 sigma of bf16-score diff noise; np-rescore set radius
#define TSIG 2.3f       // candidate threshold in row-sigma units

typedef __attribute__((ext_vector_type(8))) short sh8;
typedef __attribute__((ext_vector_type(4))) float fx4;

// ---- ws layout (bytes) ----
#define WS_XT       0ull            // ushort bf16 [32768][512] = 33554432
#define WS_XTF      33554432ull     // float [32768][512]       = 67108864
#define WS_CBT      100663296ull    // ushort bf16 [2048][512]  = 2097152
#define WS_C2F      102760448ull    // float [2048]             = 8192
#define WS_X2       102768640ull    // float [32768]            = 131072
#define WS_CNT      102899712ull    // int [32768]              = 131072
#define WS_CANDV    103030784ull    // float [32768][64]        = 8388608
#define WS_CANDS    111419392ull    // int [32768][64]          = 8388608
#define WS_ROWPART  119808000ull    // double [32768]           = 262144
#define WS_COMMIT   120070144ull    // double [16384]           = 131072
#define WS_TOTAL    120201216ull

#define TBLK 1024       // transpose blocks in k_prep (32 rows each)
#define CVTBLK 512      // cvt blocks in k_prep (4 cb rows each)

__device__ __forceinline__ unsigned short f2bf(float f) {
  union { float f; unsigned u; } x; x.f = f;
  unsigned r = x.u + 0x7fffu + ((x.u >> 16) & 1u);
  return (unsigned short)(r >> 16);
}

template <typename T>
__device__ __forceinline__ void load16_lds(const T* g, T* l) {
  __builtin_amdgcn_global_load_lds((const __attribute__((address_space(1))) void*)g,
                                   (__attribute__((address_space(3))) void*)l, 16, 0, 0);
}

// ---------------- k_prep: fused {transpose+cvt x, np x2 chain, cnt=0} + {cvt cb, c2} --
// 32-p blocks, two 256-c passes: every x-read is a 128-B contiguous segment
// (8 lanes x float4 per c-row) -> full cache-line utilization.
__global__ __launch_bounds__(256) void k_prep(const float* __restrict__ x,
                                              const float* __restrict__ cb,
                                              unsigned short* __restrict__ xT,
                                              float* __restrict__ xTf,
                                              unsigned short* __restrict__ cbT,
                                              float* __restrict__ c2f,
                                              float* __restrict__ x2ws,
                                              int* __restrict__ cnt) {
  __shared__ float tile[32][260];   // 33 KB; stride 260 floats = 1040 B (16B-aligned)
  const int tid = threadIdx.x;
  const int bx = blockIdx.x;

  if (bx < TBLK) {
    const int n = bx >> 5;
    const int p0 = (bx & 31) << 5;           // 32 p's per block
    const float* xb = x + (size_t)n * (C_ * P_) + p0;
    const int p4 = (tid & 7) << 2;           // 8 lanes x float4 = 32 p's
    const int ch = tid >> 3;                 // 32 c-rows per iteration

    float acc = 0.f;                         // np-exact x2 chain, ascending c
#pragma unroll
    for (int pass = 0; pass < 2; ++pass) {
      if (pass) __syncthreads();             // tile reuse
      // ---- load 32 p x 256 c (128-B contiguous per c-row) ----
#pragma unroll
      for (int it = 0; it < 8; ++it) {
        int cl = (it << 5) + ch;
        float4 v = *(const float4*)(xb + (size_t)(pass * 256 + cl) * P_ + p4);
        tile[p4 + 0][cl] = v.x;
        tile[p4 + 1][cl] = v.y;
        tile[p4 + 2][cl] = v.z;
        tile[p4 + 3][cl] = v.w;
      }
      __syncthreads();

      // xTf (fp32 rows) + xT (bf16 rows), contiguous writes: 32 rows x 256 c
#pragma unroll
      for (int it = 0; it < 8; ++it) {
        int idx = tid + 256 * it;            // 0..2047 float4s
        int row = idx >> 6, c4 = (idx & 63) << 2;
        float4 f = *(const float4*)&tile[row][c4];
        size_t R = (size_t)((n << 10) + p0 + row);
        size_t cg = (size_t)pass * 256 + c4;
        *(float4*)(xTf + R * C_ + cg) = f;
        ushort4 o;
        o.x = f2bf(f.x); o.y = f2bf(f.y); o.z = f2bf(f.z); o.w = f2bf(f.w);
        *(ushort4*)(xT + R * C_ + cg) = o;
      }

      // np-exact x2: strict sequential fp32 chain over c (ascending), no FMA
      if (tid < 32) {
        for (int c = 0; c < 256; ++c) {
          float t = tile[tid][c];
          acc = __fadd_rn(acc, __fmul_rn(t, t));
        }
      }
    }
    if (tid < 32) {
      int R = (n << 10) + p0 + tid;
      x2ws[R] = acc;
      cnt[R] = 0;
    }
  } else {
    // ---- cvt codebook rows to bf16 + c2 (fp64 sum of fp32 squares -> fp32) ----
    const int s = (bx - TBLK) * 4 + (tid >> 6);
    const int l = tid & 63;
    const float* row = cb + (size_t)s * C_;
    double c2d = 0.0;
#pragma unroll
    for (int h = 0; h < 2; ++h) {
      int c = h * 256 + l * 4;
      float4 v = *(const float4*)(row + c);
      ushort4 o;
      o.x = f2bf(v.x); o.y = f2bf(v.y); o.z = f2bf(v.z); o.w = f2bf(v.w);
      *(ushort4*)(cbT + (size_t)s * C_ + c) = o;
      c2d += (double)__fmul_rn(v.x, v.x) + (double)__fmul_rn(v.y, v.y) +
             (double)__fmul_rn(v.z, v.z) + (double)__fmul_rn(v.w, v.w);
    }
#pragma unroll
    for (int off = 32; off > 0; off >>= 1) c2d += __shfl_down(c2d, off);
    if (l == 0) c2f[s] = (float)c2d;
  }
}

// ---------------- MFMA GEMM + threshold epilogue -> per-row candidate lists -------
// Round-3 configuration (measured 129.7 us twice): 128x128 tile, BK=64, 4 waves,
// 4 blocks/CU. 4 blocks/CU hides staging + atomic latency under other blocks'
// MFMA (m114). Structural variants (256x256 8-phase, atomic two-pass) all lost.
// Single tweak vs round-3: the 8-shuffle segment max-reduce is only needed in
// the rare total==0 fallback -> guarded (removes ~128 DS-ops/thread common-path).
__global__ __launch_bounds__(256, 4) void k_gemm(const unsigned short* __restrict__ xT,
                                                 const unsigned short* __restrict__ cbT,
                                                 const float* __restrict__ x2ws,
                                                 float* __restrict__ candv,
                                                 int* __restrict__ cands,
                                                 int* __restrict__ cnt) {
  __shared__ unsigned short As[128 * 64];  // 16 KB, chunk (m*8 + (k8 ^ (m&7)))
  __shared__ unsigned short Bs[128 * 64];
  __shared__ float t_lds[128];
  const int tid = threadIdx.x;
  const int w = tid >> 6, l = tid & 63;
  const int bx = blockIdx.x;
  // XCD-aware swizzle: xcd = bx&7 fixed per m-tile, s-tile = (bx>>3)&15
  const int m_tile = ((bx >> 7) << 3) + (bx & 7);
  const int s_tile = (bx >> 3) & 15;
  const int m0 = m_tile << 7, s0 = s_tile << 7;
  const int wm = (w & 1) << 6, wsf = (w >> 1) << 6;
  const int quad = l >> 4, lane15 = l & 15;

  if (tid < 128) t_lds[tid] = TSIG * __fsqrt_rn(x2ws[m0 + tid]) * (1.0f / 512.0f);

  size_t gA[4], gB[4];
  unsigned short *lA[4], *lB[4];
#pragma unroll
  for (int q = 0; q < 4; ++q) {
    int chunk = (q * 4 + w) * 64 + l;
    int m = chunk >> 3, k8s = chunk & 7;
    int k8 = k8s ^ (m & 7);
    gA[q] = (size_t)(m0 + m) * (C_ * 2) + (size_t)k8 * 16;
    gB[q] = (size_t)(s0 + m) * (C_ * 2) + (size_t)k8 * 16;
    lA[q] = As + (q * 4 + w) * 512;
    lB[q] = Bs + (q * 4 + w) * 512;
  }
  const char* xb = (const char*)xT;
  const char* cbb = (const char*)cbT;

  fx4 acc[4][4];
#pragma unroll
  for (int i = 0; i < 4; ++i)
#pragma unroll
    for (int j = 0; j < 4; ++j) acc[i][j] = (fx4){0.f, 0.f, 0.f, 0.f};

  for (int kk = 0; kk < 8; ++kk) {
#pragma unroll
    for (int q = 0; q < 4; ++q) {
      load16_lds((const unsigned short*)(xb + gA[q] + (size_t)kk * 128), lA[q]);
      load16_lds((const unsigned short*)(cbb + gB[q] + (size_t)kk * 128), lB[q]);
    }
    __syncthreads();
#pragma unroll
    for (int ks = 0; ks < 2; ++ks) {
      const int k8g = ks * 4 + quad;
      sh8 af[4], bf[4];
#pragma unroll
      for (int mi = 0; mi < 4; ++mi) {
        int m = wm + mi * 16 + lane15;
        af[mi] = *(const sh8*)(As + m * 64 + (k8g ^ (m & 7)) * 8);
      }
#pragma unroll
      for (int si = 0; si < 4; ++si) {
        int s = wsf + si * 16 + lane15;
        bf[si] = *(const sh8*)(Bs + s * 64 + (k8g ^ (s & 7)) * 8);
      }
#pragma unroll
      for (int mi = 0; mi < 4; ++mi)
#pragma unroll
        for (int si = 0; si < 4; ++si)
          acc[mi][si] = __builtin_amdgcn_mfma_f32_16x16x32_bf16(af[mi], bf[si], acc[mi][si], 0, 0, 0);
    }
    __syncthreads();
  }

  // Epilogue: segment-aggregated threshold appends + per-slab row-max guarantee.
  // C/D layout: row = wm+mi*16+quad*4+r, col = s0+wsf+si*16+lane15.
  const unsigned below = (1u << lane15) - 1u;
#pragma unroll
  for (int mi = 0; mi < 4; ++mi) {
#pragma unroll
    for (int r = 0; r < 4; ++r) {
      const int rowl = wm + mi * 16 + quad * 4 + r;
      const int rowg = m0 + rowl;
      const float t = t_lds[rowl];
      float v[4]; int scol[4]; bool hit[4];
#pragma unroll
      for (int si = 0; si < 4; ++si) {
        v[si] = acc[mi][si][r];
        scol[si] = s0 + wsf + si * 16 + lane15;
        hit[si] = v[si] >= t;
      }
      int total = 0, myslot[4];
#pragma unroll
      for (int si = 0; si < 4; ++si) {
        unsigned long long b = __ballot(hit[si]);
        unsigned seg = (unsigned)((b >> (quad * 16)) & 0xFFFFull);
        myslot[si] = total + __popc(seg & below);
        total += __popc(seg);
      }
      if (total > 0) {
        int base = 0;
        if (lane15 == 0) base = atomicAdd(&cnt[rowg], total);
        base = __shfl(base, quad * 16);
#pragma unroll
        for (int si = 0; si < 4; ++si) {
          if (hit[si]) {
            int slot = base + myslot[si];
            if (slot < 64) {
              candv[(size_t)rowg * 64 + slot] = v[si];
              cands[(size_t)rowg * 64 + slot] = scol[si];
            }
          }
        }
      } else {
        // rare fallback: guarantee this slab's row-max is represented.
        float vmax = -1e30f; int smax = 0;
#pragma unroll
        for (int si = 0; si < 4; ++si) {
          if (v[si] > vmax) { vmax = v[si]; smax = scol[si]; }
        }
        // 16-lane segment max reduce (offsets < 16 stay inside the segment,
        // all 16 lanes of this segment are active in this branch)
#pragma unroll
        for (int off = 1; off < 16; off <<= 1) {
          float ov = __shfl_xor(vmax, off);
          int os = __shfl_xor(smax, off);
          if (ov > vmax) { vmax = ov; smax = os; }
        }
        int base = 0;
        if (lane15 == 0) base = atomicAdd(&cnt[rowg], 1);
        base = __shfl(base, quad * 16);
        if (lane15 == 0 && base < 64) {
          candv[(size_t)rowg * 64 + base] = vmax;
          cands[(size_t)rowg * 64 + base] = smax;
        }
      }
    }
  }
}

// ---------------- phase 2: ranks/loss from d~, lazy np-fp32 rescore for argmin ----
// Rank loop via LDS broadcast float4/int4 reads (32 DS-ops) instead of 64x2
// serial shuffles (128 DS-ops). Same comparisons, same order, identical rank.
__global__ __launch_bounds__(256, 4) void k_phase2(
    const float* __restrict__ cb, const float* __restrict__ xTf,
    const float* __restrict__ candvG, const int* __restrict__ candsG,
    const int* __restrict__ cntG, const float* __restrict__ c2f,
    const float* __restrict__ x2ws, float* __restrict__ out,
    double* __restrict__ rowpart) {
  __shared__ float xrow[4][C_];
  __shared__ float dt_l[4][64];
  __shared__ int s_l[4][64];
  const int tid = threadIdx.x;
  const int w = tid >> 6, l = tid & 63;
  const int R = blockIdx.x * 4 + w;

  const int cnt = min(cntG[R], 64);
  const float x2f = x2ws[R];
  const bool act = l < cnt;
  float v = candvG[(size_t)R * 64 + l];
  int s = candsG[(size_t)R * 64 + l];
  v = act ? v : -1e30f;
  s = act ? s : 0x7fffffff;
  const int sIdx = act ? s : 0;
  const float dt = act
      ? __fsub_rn(__fadd_rn(x2f, c2f[sIdx]), __fmul_rn(2.f, v))
      : 1e30f;

  float M = v;
#pragma unroll
  for (int off = 1; off < 64; off <<= 1) M = fmaxf(M, __shfl_xor(M, off));

  dt_l[w][l] = dt;
  s_l[w][l] = s;
  asm volatile("s_waitcnt lgkmcnt(0)" ::: "memory");  // same-wave LDS RAW

  int rank = 0;
#pragma unroll
  for (int k4 = 0; k4 < 16; ++k4) {
    float4 dk = *(const float4*)&dt_l[w][k4 * 4];
    int4 sk = *(const int4*)&s_l[w][k4 * 4];
    rank += (dk.x < dt || (dk.x == dt && sk.x < s)) ? 1 : 0;
    rank += (dk.y < dt || (dk.y == dt && sk.y < s)) ? 1 : 0;
    rank += (dk.z < dt || (dk.z == dt && sk.z < s)) ? 1 : 0;
    rank += (dk.w < dt || (dk.w == dt && sk.w < s)) ? 1 : 0;
  }

  double contrib = act ? (double)__expf(-(float)rank) * (double)dt : 0.0;
#pragma unroll
  for (int off = 32; off > 0; off >>= 1) contrib += __shfl_down(contrib, off);
  if (l == 0) rowpart[R] = contrib;

  const bool near = act && (v >= M - GUARD);
  const unsigned long long bal = __ballot(near);
  const int nres = __popcll(bal);
  if (nres == 1) {
    int src = __ffsll(bal) - 1;
    int wins = __shfl(s, src);
    if (l == 0) out[2 + R] = (float)wins;
  } else {
#pragma unroll
    for (int k = 0; k < 2; ++k)
      *(float4*)&xrow[w][l * 8 + k * 4] = *(const float4*)(xTf + (size_t)R * C_ + l * 8 + k * 4);
    float d32 = 1e30f;
    if (near) {
      const float4* crow = (const float4*)(cb + (size_t)s * C_);
      float acc = 0.f;
#pragma unroll 8
      for (int i = 0; i < C_ / 4; ++i) {
        float4 cv = crow[i];
        float4 xv = *(const float4*)&xrow[w][i * 4];
        acc = __fadd_rn(acc, __fmul_rn(xv.x, cv.x));
        acc = __fadd_rn(acc, __fmul_rn(xv.y, cv.y));
        acc = __fadd_rn(acc, __fmul_rn(xv.z, cv.z));
        acc = __fadd_rn(acc, __fmul_rn(xv.w, cv.w));
      }
      d32 = __fsub_rn(__fadd_rn(x2f, c2f[s]), __fmul_rn(2.f, acc));
    }
    float bd = d32;
    int bs2 = near ? s : 0x7fffffff;
#pragma unroll
    for (int off = 1; off < 64; off <<= 1) {
      float ov = __shfl_xor(bd, off);
      int os = __shfl_xor(bs2, off);
      if (ov < bd || (ov == bd && os < bs2)) { bd = ov; bs2 = os; }
    }
    if (l == 0) out[2 + R] = (float)bs2;
  }
}

// ---------------- K2: straight-through output + commitment loss ----------------
// p-tile-major: block = (n, 16 consecutive p's). Winner codebook rows staged
// CONTIGUOUSLY into LDS (16 x 2KB reads), eliminating the per-element random
// 4B-from-64B-line gather. Commitment partials keep the (c, aligned-4-p)
// grouping and accumulation order; only the double tree reassociates.
__global__ __launch_bounds__(256) void k2_output(
    const float* __restrict__ x, const float* __restrict__ cb,
    float* __restrict__ out, double* __restrict__ commit_partial) {
  __shared__ float qt[16][516];   // 33 KB; pad 4 -> 16B-aligned rows, <=2-way banks
  __shared__ int s_lds[16];
  __shared__ double r2[4];
  const int tid = threadIdx.x;
  const int bx = blockIdx.x;
  const int n = bx >> 6;
  const int p0 = (bx & 63) << 4;   // 16 p's per block

  if (tid < 16) s_lds[tid] = (int)out[2 + n * P_ + p0 + tid];
  __syncthreads();
  {
    const int p = tid >> 4, c0 = (tid & 15) << 2;
    const float* row = cb + (size_t)s_lds[p] * C_;
#pragma unroll
    for (int it = 0; it < 8; ++it) {
      int c = c0 + (it << 6);
      *(float4*)&qt[p][c] = *(const float4*)(row + c);
    }
  }
  __syncthreads();

  const int cl = tid >> 2, pq = (tid & 3) << 2;   // 64 c's/chunk x 4 p's/thread
  double dacc = 0.0;
#pragma unroll
  for (int chunk = 0; chunk < 8; ++chunk) {
    int c = (chunk << 6) + cl;
    const float* xr = x + ((size_t)n * C_ + c) * P_ + p0 + pq;
    float4 xv = *(const float4*)xr;
    float xs[4] = {xv.x, xv.y, xv.z, xv.w};
    float o[4];
    float acc = 0.f;
#pragma unroll
    for (int k = 0; k < 4; ++k) {
      float q = qt[pq + k][c];
      float t = __fsub_rn(q, xs[k]);
      o[k] = __fadd_rn(xs[k], t);
      float dd = __fsub_rn(xs[k], q);
      acc += dd * dd;
    }
    float* orow = out + 2 + N_ * P_ + ((size_t)n * C_ + c) * P_ + p0 + pq;
    *(float4*)orow = make_float4(o[0], o[1], o[2], o[3]);
    dacc += (double)acc;
  }

#pragma unroll
  for (int off = 32; off > 0; off >>= 1) dacc += __shfl_down(dacc, off);
  if ((tid & 63) == 0) r2[tid >> 6] = dacc;
  __syncthreads();
  if (tid == 0) commit_partial[bx] = r2[0] + r2[1] + r2[2] + r2[3];
}

// ---------------- K3: finalize scalars ----------------
__global__ __launch_bounds__(256) void k3_finalize(
    const double* __restrict__ pa, int na, const double* __restrict__ pb, int nb,
    float* __restrict__ out) {
  __shared__ double red[8];
  const int tid = threadIdx.x;
  double a = 0.0, b = 0.0;
  for (int i = tid; i < na; i += 256) a += pa[i];
  for (int i = tid; i < nb; i += 256) b += pb[i];
#pragma unroll
  for (int off = 32; off > 0; off >>= 1) {
    a += __shfl_down(a, off);
    b += __shfl_down(b, off);
  }
  if ((tid & 63) == 0) {
    red[(tid >> 6) * 2 + 0] = a;
    red[(tid >> 6) * 2 + 1] = b;
  }
  __syncthreads();
  if (tid == 0) {
    double A = red[0] + red[2] + red[4] + red[6];
    double B = red[1] + red[3] + red[5] + red[7];
    out[0] = (float)(A / ((double)N_ * (double)S_ * (double)P_));
    out[1] = (float)(B / ((double)N_ * (double)C_ * (double)P_));
  }
}

// ======================= round-2 fallback (small-ws path) =======================
#define TPW 8
#define KC 32
#define SC 64
#define KCF 48
__global__ __launch_bounds__(256) void k1_fallback(
    const float* __restrict__ x, const float* __restrict__ cb,
    float* __restrict__ out, double* __restrict__ cb_partial) {
  __shared__ float dval[TPW][KCF];
  __shared__ float x2f[TPW];
  __shared__ double redd[4];
  __shared__ float x_t[TPW][C_ + 4];
  __shared__ float cb_t[SC][KC + 4];
  __shared__ int cand_s[TPW][KCF];
  __shared__ _Float16 sc[S_][TPW];

  const int tid = threadIdx.x;
  const int bx = blockIdx.x;
  const int n = bx >> 7;
  const int p0 = (bx & 127) * TPW;

  const float* xn = x + (size_t)n * C_ * P_ + p0;
#pragma unroll
  for (int q = 0; q < 16; ++q) {
    int e = tid + 256 * q;
    int c = e >> 3, j = e & 7;
    x_t[j][c] = xn[(size_t)c * P_ + j];
  }
  __syncthreads();
  if (tid < TPW) {
    float acc = 0.f;
    for (int c = 0; c < C_; ++c)
      acc = __fadd_rn(acc, __fmul_rn(x_t[tid][c], x_t[tid][c]));
    x2f[tid] = acc;
  }
  const int j = tid & 7;
  const int sg = tid >> 3;
  for (int s0 = 0; s0 < S_; s0 += SC) {
    float acc0 = 0.f, acc1 = 0.f;
    for (int k0 = 0; k0 < C_; k0 += KC) {
      __syncthreads();
#pragma unroll
      for (int q = 0; q < 8; ++q) {
        int e = tid + 256 * q;
        int i = e >> 5, cc = e & 31;
        cb_t[i][cc] = cb[(size_t)(s0 + i) * C_ + k0 + cc];
      }
      __syncthreads();
      const float* xr = &x_t[j][k0];
#pragma unroll
      for (int cs = 0; cs < KC; cs += 4) {
        float4 xv = *(const float4*)(xr + cs);
        float4 a4 = *(const float4*)(&cb_t[sg][cs]);
        float4 b4 = *(const float4*)(&cb_t[sg + 32][cs]);
        acc0 += xv.x * a4.x + xv.y * a4.y + xv.z * a4.z + xv.w * a4.w;
        acc1 += xv.x * b4.x + xv.y * b4.y + xv.z * b4.z + xv.w * b4.w;
      }
    }
    sc[s0 + sg][j] = (_Float16)acc0;
    sc[s0 + sg + 32][j] = (_Float16)acc1;
  }
  __syncthreads();
  {
    const int g = tid >> 5, t = tid & 31;
    for (int pass = 0; pass < KCF; ++pass) {
      float bv = -1e30f;
      int bs = 0;
      for (int k = 0; k < 64; ++k) {
        int s = t + 32 * k;
        float vv = (float)sc[s][g];
        if (vv > bv) { bv = vv; bs = s; }
      }
#pragma unroll
      for (int off = 1; off < 32; off <<= 1) {
        float ov = __shfl_xor(bv, off);
        int os = __shfl_xor(bs, off);
        if (ov > bv || (ov == bv && os < bs)) { bv = ov; bs = os; }
      }
      if (t == 0) {
        cand_s[g][pass] = bs;
        sc[bs][g] = (_Float16)(-65504.f);
      }
      __syncthreads();
    }
  }
  for (int task = tid; task < TPW * KCF; task += 256) {
    int jj = task / KCF, r = task % KCF;
    int s = cand_s[jj][r];
    const float* row = cb + (size_t)s * C_;
    const float* xrw = &x_t[jj][0];
    float acc = 0.f;
    double c2d = 0.0;
    for (int c = 0; c < C_; c += 4) {
      float4 cv = *(const float4*)(row + c);
      acc = __fadd_rn(acc, __fmul_rn(xrw[c + 0], cv.x));
      acc = __fadd_rn(acc, __fmul_rn(xrw[c + 1], cv.y));
      acc = __fadd_rn(acc, __fmul_rn(xrw[c + 2], cv.z));
      acc = __fadd_rn(acc, __fmul_rn(xrw[c + 3], cv.w));
      c2d += (double)__fmul_rn(cv.x, cv.x);
      c2d += (double)__fmul_rn(cv.y, cv.y);
      c2d += (double)__fmul_rn(cv.z, cv.z);
      c2d += (double)__fmul_rn(cv.w, cv.w);
    }
    float c2s = (float)c2d;
    dval[jj][r] = __fsub_rn(__fadd_rn(x2f[jj], c2s), __fmul_rn(2.f, acc));
  }
  __syncthreads();
  double contrib = 0.0;
  for (int task = tid; task < TPW * KCF; task += 256) {
    int jj = task / KCF, r = task % KCF;
    float e = dval[jj][r];
    int s = cand_s[jj][r];
    int rank = 0;
    for (int r2 = 0; r2 < KCF; ++r2) {
      float e2 = dval[jj][r2];
      int s2 = cand_s[jj][r2];
      rank += (e2 < e || (e2 == e && s2 < s)) ? 1 : 0;
    }
    contrib += exp((double)(-rank)) * (double)e;
    if (rank == 0) out[2 + n * P_ + p0 + jj] = (float)s;
  }
  __syncthreads();
#pragma unroll
  for (int off = 32; off > 0; off >>= 1) contrib += __shfl_down(contrib, off);
  if ((tid & 63) == 0) redd[tid >> 6] = contrib;
  __syncthreads();
  if (tid == 0) cb_partial[bx] = redd[0] + redd[1] + redd[2] + redd[3];
}

extern "C" void kernel_launch(void* const* d_in, const int* in_sizes, int n_in,
                              void* d_out, int out_size, void* d_ws, size_t ws_size,
                              hipStream_t stream) {
  const float* x = (const float*)d_in[0];
  const float* cb = (const float*)d_in[1];
  float* out = (float*)d_out;
  char* ws = (char*)d_ws;

  if (ws_size >= WS_TOTAL) {
    unsigned short* xT = (unsigned short*)(ws + WS_XT);
    float* xTf = (float*)(ws + WS_XTF);
    unsigned short* cbT = (unsigned short*)(ws + WS_CBT);
    float* c2f = (float*)(ws + WS_C2F);
    float* x2ws = (float*)(ws + WS_X2);
    int* cnt = (int*)(ws + WS_CNT);
    float* candv = (float*)(ws + WS_CANDV);
    int* cands = (int*)(ws + WS_CANDS);
    double* rowpart = (double*)(ws + WS_ROWPART);
    double* commitp = (double*)(ws + WS_COMMIT);

    hipLaunchKernelGGL(k_prep, dim3(TBLK + CVTBLK), dim3(256), 0, stream,
                       x, cb, xT, xTf, cbT, c2f, x2ws, cnt);
    hipLaunchKernelGGL(k_gemm, dim3(4096), dim3(256), 0, stream,
                       xT, cbT, x2ws, candv, cands, cnt);
    hipLaunchKernelGGL(k_phase2, dim3(NR_ / 4), dim3(256), 0, stream,
                       cb, xTf, candv, cands, cnt, c2f, x2ws, out, rowpart);
    hipLaunchKernelGGL(k2_output, dim3(2048), dim3(256), 0, stream, x, cb, out, commitp);
    hipLaunchKernelGGL(k3_finalize, dim3(1), dim3(256), 0, stream,
                       rowpart, NR_, commitp, 2048, out);
  } else {
    double* cb_partial = (double*)d_ws;
    double* commitp = cb_partial + 4096;
    hipLaunchKernelGGL(k1_fallback, dim3(4096), dim3(256), 0, stream, x, cb, out, cb_partial);
    hipLaunchKernelGGL(k2_output, dim3(2048), dim3(256), 0, stream, x, cb, out, commitp);
    hipLaunchKernelGGL(k3_finalize, dim3(1), dim3(256), 0, stream,
                       cb_partial, 4096, commitp, 2048, out);
  }
}

// Round 7
// 412.023 us; speedup vs baseline: 1.1139x; 1.0835x over previous
//
#include <hip/hip_runtime.h>
#include <hip/hip_fp16.h>

#define N_ 32
#define C_ 512
#define P_ 1024
#define S_ 2048
#define NR_ (N_ * P_)   // 32768 rows
#define GUARD 6e-3f     // ~30 sigma of bf16-score diff noise; np-rescore set radius
#define TSIG 2.3f       // candidate threshold in row-sigma units

typedef __attribute__((ext_vector_type(8))) short sh8;
typedef __attribute__((ext_vector_type(4))) float fx4;

// ---- ws layout (bytes) ----
#define WS_XT       0ull            // ushort bf16 [32768][512] = 33554432
#define WS_XTF      33554432ull     // float [32768][512]       = 67108864
#define WS_CBT      100663296ull    // ushort bf16 [2048][512]  = 2097152
#define WS_C2F      102760448ull    // float [2048]             = 8192
#define WS_X2       102768640ull    // float [32768]            = 131072
#define WS_CNT      102899712ull    // int [32768]              = 131072
#define WS_CANDV    103030784ull    // float [32768][64]        = 8388608
#define WS_CANDS    111419392ull    // int [32768][64]          = 8388608
#define WS_ROWPART  119808000ull    // double [8192 used]       = 262144
#define WS_COMMIT   120070144ull    // double [16384 avail]     = 131072
#define WS_TOTAL    120201216ull

#define TBLK 1024       // transpose blocks in k_prep (32 rows each)
#define CVTBLK 512      // cvt blocks in k_prep (4 cb rows each)

__device__ __forceinline__ unsigned short f2bf(float f) {
  union { float f; unsigned u; } x; x.f = f;
  unsigned r = x.u + 0x7fffu + ((x.u >> 16) & 1u);
  return (unsigned short)(r >> 16);
}

template <typename T>
__device__ __forceinline__ void load16_lds(const T* g, T* l) {
  __builtin_amdgcn_global_load_lds((const __attribute__((address_space(1))) void*)g,
                                   (__attribute__((address_space(3))) void*)l, 16, 0, 0);
}

// ---------------- k_prep: fused {transpose+cvt x, np x2 chain, cnt=0} + {cvt cb, c2} --
// 32-p blocks, two 256-c passes: every x-read is a 128-B contiguous segment
// (8 lanes x float4 per c-row) -> full cache-line utilization.
__global__ __launch_bounds__(256) void k_prep(const float* __restrict__ x,
                                              const float* __restrict__ cb,
                                              unsigned short* __restrict__ xT,
                                              float* __restrict__ xTf,
                                              unsigned short* __restrict__ cbT,
                                              float* __restrict__ c2f,
                                              float* __restrict__ x2ws,
                                              int* __restrict__ cnt) {
  __shared__ float tile[32][260];   // 33 KB; stride 260 floats = 1040 B (16B-aligned)
  const int tid = threadIdx.x;
  const int bx = blockIdx.x;

  if (bx < TBLK) {
    const int n = bx >> 5;
    const int p0 = (bx & 31) << 5;           // 32 p's per block
    const float* xb = x + (size_t)n * (C_ * P_) + p0;
    const int p4 = (tid & 7) << 2;           // 8 lanes x float4 = 32 p's
    const int ch = tid >> 3;                 // 32 c-rows per iteration

    float acc = 0.f;                         // np-exact x2 chain, ascending c
#pragma unroll
    for (int pass = 0; pass < 2; ++pass) {
      if (pass) __syncthreads();             // tile reuse
      // ---- load 32 p x 256 c (128-B contiguous per c-row) ----
#pragma unroll
      for (int it = 0; it < 8; ++it) {
        int cl = (it << 5) + ch;
        float4 v = *(const float4*)(xb + (size_t)(pass * 256 + cl) * P_ + p4);
        tile[p4 + 0][cl] = v.x;
        tile[p4 + 1][cl] = v.y;
        tile[p4 + 2][cl] = v.z;
        tile[p4 + 3][cl] = v.w;
      }
      __syncthreads();

      // xTf (fp32 rows) + xT (bf16 rows), contiguous writes: 32 rows x 256 c
#pragma unroll
      for (int it = 0; it < 8; ++it) {
        int idx = tid + 256 * it;            // 0..2047 float4s
        int row = idx >> 6, c4 = (idx & 63) << 2;
        float4 f = *(const float4*)&tile[row][c4];
        size_t R = (size_t)((n << 10) + p0 + row);
        size_t cg = (size_t)pass * 256 + c4;
        *(float4*)(xTf + R * C_ + cg) = f;
        ushort4 o;
        o.x = f2bf(f.x); o.y = f2bf(f.y); o.z = f2bf(f.z); o.w = f2bf(f.w);
        *(ushort4*)(xT + R * C_ + cg) = o;
      }

      // np-exact x2: strict sequential fp32 chain over c (ascending), no FMA
      if (tid < 32) {
        for (int c = 0; c < 256; ++c) {
          float t = tile[tid][c];
          acc = __fadd_rn(acc, __fmul_rn(t, t));
        }
      }
    }
    if (tid < 32) {
      int R = (n << 10) + p0 + tid;
      x2ws[R] = acc;
      cnt[R] = 0;
    }
  } else {
    // ---- cvt codebook rows to bf16 + c2 (fp64 sum of fp32 squares -> fp32) ----
    const int s = (bx - TBLK) * 4 + (tid >> 6);
    const int l = tid & 63;
    const float* row = cb + (size_t)s * C_;
    double c2d = 0.0;
#pragma unroll
    for (int h = 0; h < 2; ++h) {
      int c = h * 256 + l * 4;
      float4 v = *(const float4*)(row + c);
      ushort4 o;
      o.x = f2bf(v.x); o.y = f2bf(v.y); o.z = f2bf(v.z); o.w = f2bf(v.w);
      *(ushort4*)(cbT + (size_t)s * C_ + c) = o;
      c2d += (double)__fmul_rn(v.x, v.x) + (double)__fmul_rn(v.y, v.y) +
             (double)__fmul_rn(v.z, v.z) + (double)__fmul_rn(v.w, v.w);
    }
#pragma unroll
    for (int off = 32; off > 0; off >>= 1) c2d += __shfl_down(c2d, off);
    if (l == 0) c2f[s] = (float)c2d;
  }
}

// ---------------- MFMA GEMM + threshold epilogue -> per-row candidate lists -------
// LOCKED: byte-exact round-3 configuration (measured 129.7 us twice).
// 128x128 tile, BK=64, 4 waves, 4 blocks/CU. All epilogue variants (packed uint2,
// two-pass atomics, guarded max-reduce) regressed: at 4 blocks/CU latency is
// hidden by co-resident blocks' MFMA; only added work/branches show up.
__global__ __launch_bounds__(256, 4) void k_gemm(const unsigned short* __restrict__ xT,
                                                 const unsigned short* __restrict__ cbT,
                                                 const float* __restrict__ x2ws,
                                                 float* __restrict__ candv,
                                                 int* __restrict__ cands,
                                                 int* __restrict__ cnt) {
  __shared__ unsigned short As[128 * 64];  // 16 KB, chunk (m*8 + (k8 ^ (m&7)))
  __shared__ unsigned short Bs[128 * 64];
  __shared__ float t_lds[128];
  const int tid = threadIdx.x;
  const int w = tid >> 6, l = tid & 63;
  const int bx = blockIdx.x;
  // XCD-aware swizzle: xcd = bx&7 fixed per m-tile, s-tile = (bx>>3)&15
  const int m_tile = ((bx >> 7) << 3) + (bx & 7);
  const int s_tile = (bx >> 3) & 15;
  const int m0 = m_tile << 7, s0 = s_tile << 7;
  const int wm = (w & 1) << 6, wsf = (w >> 1) << 6;
  const int quad = l >> 4, lane15 = l & 15;

  if (tid < 128) t_lds[tid] = TSIG * __fsqrt_rn(x2ws[m0 + tid]) * (1.0f / 512.0f);

  size_t gA[4], gB[4];
  unsigned short *lA[4], *lB[4];
#pragma unroll
  for (int q = 0; q < 4; ++q) {
    int chunk = (q * 4 + w) * 64 + l;
    int m = chunk >> 3, k8s = chunk & 7;
    int k8 = k8s ^ (m & 7);
    gA[q] = (size_t)(m0 + m) * (C_ * 2) + (size_t)k8 * 16;
    gB[q] = (size_t)(s0 + m) * (C_ * 2) + (size_t)k8 * 16;
    lA[q] = As + (q * 4 + w) * 512;
    lB[q] = Bs + (q * 4 + w) * 512;
  }
  const char* xb = (const char*)xT;
  const char* cbb = (const char*)cbT;

  fx4 acc[4][4];
#pragma unroll
  for (int i = 0; i < 4; ++i)
#pragma unroll
    for (int j = 0; j < 4; ++j) acc[i][j] = (fx4){0.f, 0.f, 0.f, 0.f};

  for (int kk = 0; kk < 8; ++kk) {
#pragma unroll
    for (int q = 0; q < 4; ++q) {
      load16_lds((const unsigned short*)(xb + gA[q] + (size_t)kk * 128), lA[q]);
      load16_lds((const unsigned short*)(cbb + gB[q] + (size_t)kk * 128), lB[q]);
    }
    __syncthreads();
#pragma unroll
    for (int ks = 0; ks < 2; ++ks) {
      const int k8g = ks * 4 + quad;
      sh8 af[4], bf[4];
#pragma unroll
      for (int mi = 0; mi < 4; ++mi) {
        int m = wm + mi * 16 + lane15;
        af[mi] = *(const sh8*)(As + m * 64 + (k8g ^ (m & 7)) * 8);
      }
#pragma unroll
      for (int si = 0; si < 4; ++si) {
        int s = wsf + si * 16 + lane15;
        bf[si] = *(const sh8*)(Bs + s * 64 + (k8g ^ (s & 7)) * 8);
      }
#pragma unroll
      for (int mi = 0; mi < 4; ++mi)
#pragma unroll
        for (int si = 0; si < 4; ++si)
          acc[mi][si] = __builtin_amdgcn_mfma_f32_16x16x32_bf16(af[mi], bf[si], acc[mi][si], 0, 0, 0);
    }
    __syncthreads();
  }

  // Epilogue: segment-aggregated threshold appends + per-slab row-max guarantee.
  // C/D layout: row = wm+mi*16+quad*4+r, col = s0+wsf+si*16+lane15.
  const unsigned below = (1u << lane15) - 1u;
#pragma unroll
  for (int mi = 0; mi < 4; ++mi) {
#pragma unroll
    for (int r = 0; r < 4; ++r) {
      const int rowl = wm + mi * 16 + quad * 4 + r;
      const int rowg = m0 + rowl;
      const float t = t_lds[rowl];
      float v[4]; int scol[4]; bool hit[4];
      float vmax = -1e30f; int smax = 0;
#pragma unroll
      for (int si = 0; si < 4; ++si) {
        v[si] = acc[mi][si][r];
        scol[si] = s0 + wsf + si * 16 + lane15;
        hit[si] = v[si] >= t;
        if (v[si] > vmax) { vmax = v[si]; smax = scol[si]; }
      }
      int total = 0, myslot[4];
#pragma unroll
      for (int si = 0; si < 4; ++si) {
        unsigned long long b = __ballot(hit[si]);
        unsigned seg = (unsigned)((b >> (quad * 16)) & 0xFFFFull);
        myslot[si] = total + __popc(seg & below);
        total += __popc(seg);
      }
      // 16-lane segment max reduce (offsets < 16 stay in segment)
#pragma unroll
      for (int off = 1; off < 16; off <<= 1) {
        float ov = __shfl_xor(vmax, off);
        int os = __shfl_xor(smax, off);
        if (ov > vmax) { vmax = ov; smax = os; }
      }
      int base = 0;
      if (lane15 == 0) base = atomicAdd(&cnt[rowg], total > 0 ? total : 1);
      base = __shfl(base, quad * 16);
      if (total > 0) {
#pragma unroll
        for (int si = 0; si < 4; ++si) {
          if (hit[si]) {
            int slot = base + myslot[si];
            if (slot < 64) {
              candv[(size_t)rowg * 64 + slot] = v[si];
              cands[(size_t)rowg * 64 + slot] = scol[si];
            }
          }
        }
      } else if (lane15 == 0 && base < 64) {
        candv[(size_t)rowg * 64 + base] = vmax;
        cands[(size_t)rowg * 64 + base] = smax;
      }
    }
  }
}

// ---------------- phase 2: ranks/loss from d~, lazy np-fp32 rescore for argmin ----
// Rank loop via LDS broadcast float4/int4 reads; rowpart now PER-BLOCK (4 rows
// pre-summed in fp64) -> k3 reads 8192 doubles instead of 32768.
__global__ __launch_bounds__(256, 4) void k_phase2(
    const float* __restrict__ cb, const float* __restrict__ xTf,
    const float* __restrict__ candvG, const int* __restrict__ candsG,
    const int* __restrict__ cntG, const float* __restrict__ c2f,
    const float* __restrict__ x2ws, float* __restrict__ out,
    double* __restrict__ rowpart) {
  __shared__ float xrow[4][C_];
  __shared__ float dt_l[4][64];
  __shared__ int s_l[4][64];
  __shared__ double cpart[4];
  const int tid = threadIdx.x;
  const int w = tid >> 6, l = tid & 63;
  const int R = blockIdx.x * 4 + w;

  const int cnt = min(cntG[R], 64);
  const float x2f = x2ws[R];
  const bool act = l < cnt;
  float v = candvG[(size_t)R * 64 + l];
  int s = candsG[(size_t)R * 64 + l];
  v = act ? v : -1e30f;
  s = act ? s : 0x7fffffff;
  const int sIdx = act ? s : 0;
  const float dt = act
      ? __fsub_rn(__fadd_rn(x2f, c2f[sIdx]), __fmul_rn(2.f, v))
      : 1e30f;

  float M = v;
#pragma unroll
  for (int off = 1; off < 64; off <<= 1) M = fmaxf(M, __shfl_xor(M, off));

  dt_l[w][l] = dt;
  s_l[w][l] = s;
  asm volatile("s_waitcnt lgkmcnt(0)" ::: "memory");  // same-wave LDS RAW

  int rank = 0;
#pragma unroll
  for (int k4 = 0; k4 < 16; ++k4) {
    float4 dk = *(const float4*)&dt_l[w][k4 * 4];
    int4 sk = *(const int4*)&s_l[w][k4 * 4];
    rank += (dk.x < dt || (dk.x == dt && sk.x < s)) ? 1 : 0;
    rank += (dk.y < dt || (dk.y == dt && sk.y < s)) ? 1 : 0;
    rank += (dk.z < dt || (dk.z == dt && sk.z < s)) ? 1 : 0;
    rank += (dk.w < dt || (dk.w == dt && sk.w < s)) ? 1 : 0;
  }

  double contrib = act ? (double)__expf(-(float)rank) * (double)dt : 0.0;
#pragma unroll
  for (int off = 32; off > 0; off >>= 1) contrib += __shfl_down(contrib, off);
  if (l == 0) cpart[w] = contrib;

  const bool near = act && (v >= M - GUARD);
  const unsigned long long bal = __ballot(near);
  const int nres = __popcll(bal);
  if (nres == 1) {
    int src = __ffsll(bal) - 1;
    int wins = __shfl(s, src);
    if (l == 0) out[2 + R] = (float)wins;
  } else {
#pragma unroll
    for (int k = 0; k < 2; ++k)
      *(float4*)&xrow[w][l * 8 + k * 4] = *(const float4*)(xTf + (size_t)R * C_ + l * 8 + k * 4);
    float d32 = 1e30f;
    if (near) {
      const float4* crow = (const float4*)(cb + (size_t)s * C_);
      float acc = 0.f;
#pragma unroll 8
      for (int i = 0; i < C_ / 4; ++i) {
        float4 cv = crow[i];
        float4 xv = *(const float4*)&xrow[w][i * 4];
        acc = __fadd_rn(acc, __fmul_rn(xv.x, cv.x));
        acc = __fadd_rn(acc, __fmul_rn(xv.y, cv.y));
        acc = __fadd_rn(acc, __fmul_rn(xv.z, cv.z));
        acc = __fadd_rn(acc, __fmul_rn(xv.w, cv.w));
      }
      d32 = __fsub_rn(__fadd_rn(x2f, c2f[s]), __fmul_rn(2.f, acc));
    }
    float bd = d32;
    int bs2 = near ? s : 0x7fffffff;
#pragma unroll
    for (int off = 1; off < 64; off <<= 1) {
      float ov = __shfl_xor(bd, off);
      int os = __shfl_xor(bs2, off);
      if (ov < bd || (ov == bd && os < bs2)) { bd = ov; bs2 = os; }
    }
    if (l == 0) out[2 + R] = (float)bs2;
  }

  __syncthreads();
  if (tid == 0) rowpart[blockIdx.x] = cpart[0] + cpart[1] + cpart[2] + cpart[3];
}

// ---------------- K2: straight-through output + commitment loss ----------------
// 32-p blocks, 512 threads: every x-read AND out-write per (n,c) is a full
// 128-B cache line (was 64-B half-lines with 16-p blocks -> sector RMW risk).
// Winner codebook rows staged contiguously in LDS (32 x 2KB). Per-thread
// (c, aligned-4-p) fp32 grouping preserved; only the fp64 tree reassociates.
__global__ __launch_bounds__(512) void k2_output(
    const float* __restrict__ x, const float* __restrict__ cb,
    float* __restrict__ out, double* __restrict__ commit_partial) {
  __shared__ float qt[32][516];   // 66 KB; pad 4 -> 16B-aligned rows, 2 blocks/CU
  __shared__ int s_lds[32];
  __shared__ double r2[8];
  const int tid = threadIdx.x;
  const int bx = blockIdx.x;
  const int n = bx >> 5;
  const int p0 = (bx & 31) << 5;   // 32 p's per block

  if (tid < 32) s_lds[tid] = (int)out[2 + n * P_ + p0 + tid];
  __syncthreads();
  {
    const int p = tid >> 4, c0 = (tid & 15) << 2;   // 32 rows x 16 lanes
    const float* row = cb + (size_t)s_lds[p] * C_;
#pragma unroll
    for (int it = 0; it < 8; ++it) {
      int c = c0 + (it << 6);
      *(float4*)&qt[p][c] = *(const float4*)(row + c);
    }
  }
  __syncthreads();

  const int cl = tid >> 3, pq = (tid & 7) << 2;   // 64 c's/chunk x 8 p-groups
  double dacc = 0.0;
#pragma unroll
  for (int chunk = 0; chunk < 8; ++chunk) {
    int c = (chunk << 6) + cl;
    const float* xr = x + ((size_t)n * C_ + c) * P_ + p0 + pq;
    float4 xv = *(const float4*)xr;
    float xs[4] = {xv.x, xv.y, xv.z, xv.w};
    float o[4];
    float acc = 0.f;
#pragma unroll
    for (int k = 0; k < 4; ++k) {
      float q = qt[pq + k][c];
      float t = __fsub_rn(q, xs[k]);
      o[k] = __fadd_rn(xs[k], t);
      float dd = __fsub_rn(xs[k], q);
      acc += dd * dd;
    }
    float* orow = out + 2 + N_ * P_ + ((size_t)n * C_ + c) * P_ + p0 + pq;
    *(float4*)orow = make_float4(o[0], o[1], o[2], o[3]);
    dacc += (double)acc;
  }

#pragma unroll
  for (int off = 32; off > 0; off >>= 1) dacc += __shfl_down(dacc, off);
  if ((tid & 63) == 0) r2[tid >> 6] = dacc;
  __syncthreads();
  if (tid == 0) {
    double t = 0.0;
#pragma unroll
    for (int i = 0; i < 8; ++i) t += r2[i];
    commit_partial[bx] = t;
  }
}

// ---------------- K3: finalize scalars ----------------
__global__ __launch_bounds__(256) void k3_finalize(
    const double* __restrict__ pa, int na, const double* __restrict__ pb, int nb,
    float* __restrict__ out) {
  __shared__ double red[8];
  const int tid = threadIdx.x;
  double a = 0.0, b = 0.0;
  for (int i = tid; i < na; i += 256) a += pa[i];
  for (int i = tid; i < nb; i += 256) b += pb[i];
#pragma unroll
  for (int off = 32; off > 0; off >>= 1) {
    a += __shfl_down(a, off);
    b += __shfl_down(b, off);
  }
  if ((tid & 63) == 0) {
    red[(tid >> 6) * 2 + 0] = a;
    red[(tid >> 6) * 2 + 1] = b;
  }
  __syncthreads();
  if (tid == 0) {
    double A = red[0] + red[2] + red[4] + red[6];
    double B = red[1] + red[3] + red[5] + red[7];
    out[0] = (float)(A / ((double)N_ * (double)S_ * (double)P_));
    out[1] = (float)(B / ((double)N_ * (double)C_ * (double)P_));
  }
}

// ======================= round-2 fallback (small-ws path) =======================
#define TPW 8
#define KC 32
#define SC 64
#define KCF 48
__global__ __launch_bounds__(256) void k1_fallback(
    const float* __restrict__ x, const float* __restrict__ cb,
    float* __restrict__ out, double* __restrict__ cb_partial) {
  __shared__ float dval[TPW][KCF];
  __shared__ float x2f[TPW];
  __shared__ double redd[4];
  __shared__ float x_t[TPW][C_ + 4];
  __shared__ float cb_t[SC][KC + 4];
  __shared__ int cand_s[TPW][KCF];
  __shared__ _Float16 sc[S_][TPW];

  const int tid = threadIdx.x;
  const int bx = blockIdx.x;
  const int n = bx >> 7;
  const int p0 = (bx & 127) * TPW;

  const float* xn = x + (size_t)n * C_ * P_ + p0;
#pragma unroll
  for (int q = 0; q < 16; ++q) {
    int e = tid + 256 * q;
    int c = e >> 3, j = e & 7;
    x_t[j][c] = xn[(size_t)c * P_ + j];
  }
  __syncthreads();
  if (tid < TPW) {
    float acc = 0.f;
    for (int c = 0; c < C_; ++c)
      acc = __fadd_rn(acc, __fmul_rn(x_t[tid][c], x_t[tid][c]));
    x2f[tid] = acc;
  }
  const int j = tid & 7;
  const int sg = tid >> 3;
  for (int s0 = 0; s0 < S_; s0 += SC) {
    float acc0 = 0.f, acc1 = 0.f;
    for (int k0 = 0; k0 < C_; k0 += KC) {
      __syncthreads();
#pragma unroll
      for (int q = 0; q < 8; ++q) {
        int e = tid + 256 * q;
        int i = e >> 5, cc = e & 31;
        cb_t[i][cc] = cb[(size_t)(s0 + i) * C_ + k0 + cc];
      }
      __syncthreads();
      const float* xr = &x_t[j][k0];
#pragma unroll
      for (int cs = 0; cs < KC; cs += 4) {
        float4 xv = *(const float4*)(xr + cs);
        float4 a4 = *(const float4*)(&cb_t[sg][cs]);
        float4 b4 = *(const float4*)(&cb_t[sg + 32][cs]);
        acc0 += xv.x * a4.x + xv.y * a4.y + xv.z * a4.z + xv.w * a4.w;
        acc1 += xv.x * b4.x + xv.y * b4.y + xv.z * b4.z + xv.w * b4.w;
      }
    }
    sc[s0 + sg][j] = (_Float16)acc0;
    sc[s0 + sg + 32][j] = (_Float16)acc1;
  }
  __syncthreads();
  {
    const int g = tid >> 5, t = tid & 31;
    for (int pass = 0; pass < KCF; ++pass) {
      float bv = -1e30f;
      int bs = 0;
      for (int k = 0; k < 64; ++k) {
        int s = t + 32 * k;
        float vv = (float)sc[s][g];
        if (vv > bv) { bv = vv; bs = s; }
      }
#pragma unroll
      for (int off = 1; off < 32; off <<= 1) {
        float ov = __shfl_xor(bv, off);
        int os = __shfl_xor(bs, off);
        if (ov > bv || (ov == bv && os < bs)) { bv = ov; bs = os; }
      }
      if (t == 0) {
        cand_s[g][pass] = bs;
        sc[bs][g] = (_Float16)(-65504.f);
      }
      __syncthreads();
    }
  }
  for (int task = tid; task < TPW * KCF; task += 256) {
    int jj = task / KCF, r = task % KCF;
    int s = cand_s[jj][r];
    const float* row = cb + (size_t)s * C_;
    const float* xrw = &x_t[jj][0];
    float acc = 0.f;
    double c2d = 0.0;
    for (int c = 0; c < C_; c += 4) {
      float4 cv = *(const float4*)(row + c);
      acc = __fadd_rn(acc, __fmul_rn(xrw[c + 0], cv.x));
      acc = __fadd_rn(acc, __fmul_rn(xrw[c + 1], cv.y));
      acc = __fadd_rn(acc, __fmul_rn(xrw[c + 2], cv.z));
      acc = __fadd_rn(acc, __fmul_rn(xrw[c + 3], cv.w));
      c2d += (double)__fmul_rn(cv.x, cv.x);
      c2d += (double)__fmul_rn(cv.y, cv.y);
      c2d += (double)__fmul_rn(cv.z, cv.z);
      c2d += (double)__fmul_rn(cv.w, cv.w);
    }
    float c2s = (float)c2d;
    dval[jj][r] = __fsub_rn(__fadd_rn(x2f[jj], c2s), __fmul_rn(2.f, acc));
  }
  __syncthreads();
  double contrib = 0.0;
  for (int task = tid; task < TPW * KCF; task += 256) {
    int jj = task / KCF, r = task % KCF;
    float e = dval[jj][r];
    int s = cand_s[jj][r];
    int rank = 0;
    for (int r2 = 0; r2 < KCF; ++r2) {
      float e2 = dval[jj][r2];
      int s2 = cand_s[jj][r2];
      rank += (e2 < e || (e2 == e && s2 < s)) ? 1 : 0;
    }
    contrib += exp((double)(-rank)) * (double)e;
    if (rank == 0) out[2 + n * P_ + p0 + jj] = (float)s;
  }
  __syncthreads();
#pragma unroll
  for (int off = 32; off > 0; off >>= 1) contrib += __shfl_down(contrib, off);
  if ((tid & 63) == 0) redd[tid >> 6] = contrib;
  __syncthreads();
  if (tid == 0) cb_partial[bx] = redd[0] + redd[1] + redd[2] + redd[3];
}

extern "C" void kernel_launch(void* const* d_in, const int* in_sizes, int n_in,
                              void* d_out, int out_size, void* d_ws, size_t ws_size,
                              hipStream_t stream) {
  const float* x = (const float*)d_in[0];
  const float* cb = (const float*)d_in[1];
  float* out = (float*)d_out;
  char* ws = (char*)d_ws;

  if (ws_size >= WS_TOTAL) {
    unsigned short* xT = (unsigned short*)(ws + WS_XT);
    float* xTf = (float*)(ws + WS_XTF);
    unsigned short* cbT = (unsigned short*)(ws + WS_CBT);
    float* c2f = (float*)(ws + WS_C2F);
    float* x2ws = (float*)(ws + WS_X2);
    int* cnt = (int*)(ws + WS_CNT);
    float* candv = (float*)(ws + WS_CANDV);
    int* cands = (int*)(ws + WS_CANDS);
    double* rowpart = (double*)(ws + WS_ROWPART);
    double* commitp = (double*)(ws + WS_COMMIT);

    hipLaunchKernelGGL(k_prep, dim3(TBLK + CVTBLK), dim3(256), 0, stream,
                       x, cb, xT, xTf, cbT, c2f, x2ws, cnt);
    hipLaunchKernelGGL(k_gemm, dim3(4096), dim3(256), 0, stream,
                       xT, cbT, x2ws, candv, cands, cnt);
    hipLaunchKernelGGL(k_phase2, dim3(NR_ / 4), dim3(256), 0, stream,
                       cb, xTf, candv, cands, cnt, c2f, x2ws, out, rowpart);
    hipLaunchKernelGGL(k2_output, dim3(1024), dim3(512), 0, stream, x, cb, out, commitp);
    hipLaunchKernelGGL(k3_finalize, dim3(1), dim3(256), 0, stream,
                       rowpart, NR_ / 4, commitp, 1024, out);
  } else {
    double* cb_partial = (double*)d_ws;
    double* commitp = cb_partial + 4096;
    hipLaunchKernelGGL(k1_fallback, dim3(4096), dim3(256), 0, stream, x, cb, out, cb_partial);
    hipLaunchKernelGGL(k2_output, dim3(1024), dim3(512), 0, stream, x, cb, out, commitp);
    hipLaunchKernelGGL(k3_finalize, dim3(1), dim3(256), 0, stream,
                       cb_partial, 4096, commitp, 1024, out);
  }
}